// Round 7
// baseline (227.678 us; speedup 1.0000x reference)
//
#include <hip/hip_runtime.h>

#define NB 128
#define CC 1024
#define HWP 196
#define HH 14
#define OO 256

typedef unsigned short ushort_t;
typedef __attribute__((ext_vector_type(8))) short short8;
typedef __attribute__((ext_vector_type(4))) float float4v;

__device__ __forceinline__ ushort_t f2bf(float v) {
  union { float f; unsigned int u; } c; c.f = v;
  unsigned int u = c.u;
  unsigned int r = (u + 0x7FFFu + ((u >> 16) & 1u)) >> 16;   // RNE
  return (ushort_t)r;
}

// K1: fused (a) partial channel-sum (UNCHANGED bit-exact FP order — medK rank
// selection is knife-edge sensitive; do NOT reorder the c loop), (b) weight
// bf16 cast, (c) x -> xT[n][p][c] bf16 transpose (kills k_main's scattered
// gather: 200 MB line-granular L3 traffic -> 8 MB coalesced).
// Blocks 0..255: reduce. 256..2303: cast. 2304..3327: transpose.
__global__ __launch_bounds__(256) void k_prep(const float* __restrict__ x,
                                              const float* __restrict__ wmax,
                                              const float* __restrict__ wmed,
                                              float* __restrict__ partial,
                                              ushort_t* __restrict__ wb,
                                              ushort_t* __restrict__ xT) {
  const int b = blockIdx.x, t = threadIdx.x;
  if (b >= 2304) {   // transpose: one block per (n, cg)
    __shared__ alignas(16) float lds_t[32 * 200];   // 25.6 KB, padded rows
    const int u2 = b - 2304;
    const int n = u2 >> 3, cg = u2 & 7;
    for (int ch = 0; ch < 4; ++ch) {                // 4 chunks of 32 channels
      const float4* src = (const float4*)(x + ((size_t)n * CC + (size_t)cg * 128 + ch * 32) * HWP);
      __syncthreads();                              // lds_t reuse
      for (int idx = t; idx < 32 * 49; idx += 256) {
        int r = idx / 49, q = idx - r * 49;
        *(float4*)&lds_t[r * 200 + q * 4] = src[idx];
      }
      __syncthreads();
      if (t < HWP) {
        const int p = t;
        ushort_t* dst = xT + ((size_t)n * HWP + p) * CC + cg * 128 + ch * 32;
        #pragma unroll
        for (int c8 = 0; c8 < 4; ++c8) {
          union { short8 v; ushort_t s[8]; } pk;
          #pragma unroll
          for (int e = 0; e < 8; ++e)
            pk.s[e] = f2bf(lds_t[(c8 * 8 + e) * 200 + p]);
          *reinterpret_cast<short8*>(dst + c8 * 8) = pk.v;
        }
      }
    }
    return;
  }
  if (b >= 256) {   // weight cast: 2048 blocks x 256 = 2*OO*CC elements
    int idx = (b - 256) * 256 + t;
    int z = idx >> 18;
    int r = idx & (OO * CC - 1);
    const float* w = z ? wmed : wmax;
    wb[idx] = f2bf(w[r]);
    return;
  }
  // reduce: one wave per (n,cg); lanes 0..48 hold float4 (4 consecutive p).
  const int unit = b * 4 + (t >> 6);
  const int lane = t & 63;
  if (lane >= 49) return;
  const int n = unit >> 3, cg = unit & 7;
  const float4* base = (const float4*)(x + ((size_t)n * CC + (size_t)cg * 128) * HWP);
  float4 s = {0.f, 0.f, 0.f, 0.f};
  #pragma unroll 16
  for (int c = 0; c < 128; ++c) {
    float4 v = base[c * 49 + lane];
    s.x += v.x; s.y += v.y; s.z += v.z; s.w += v.w;   // per-p sequential order
  }
  ((float4*)(partial + ((size_t)n * 8 + cg) * HWP))[lane] = s;
}

// K2: per (n,z) block, 512 threads: in-block exact stable rank-select;
// coalesced A-row copy from xT (32 KB/block); bf16 MFMA GEMM (8 waves x 32
// cols); BN+ReLU; Lnorm apply; writes graphs (+ rows/cols from z==0 blocks).
__global__ __launch_bounds__(512, 2) void k_main(
    const ushort_t* __restrict__ xT, const float* __restrict__ partial,
    const ushort_t* __restrict__ wb,
    const float* __restrict__ g_max, const float* __restrict__ b_max,
    const float* __restrict__ m_max, const float* __restrict__ v_max,
    const float* __restrict__ g_med, const float* __restrict__ b_med,
    const float* __restrict__ m_med, const float* __restrict__ v_med,
    float* __restrict__ out) {
  constexpr int AP = 1032;               // padded row stride (ushorts)
  __shared__ alignas(16) ushort_t A_sh[16 * AP];   // 33 KB
  __shared__ float fre[HWP];
  __shared__ int sc[32];
  __shared__ float Lsh[16][17];
  __shared__ float dinv[16];
  __shared__ float y_sh[16][257];        // 16.4 KB

  const int n = blockIdx.x;
  const int z = blockIdx.y;
  const int t = threadIdx.x;

  // ---- select: fre = sum of 8 partials (sequential); stable ranks ----
  if (t < HWP) {
    float s = 0.f;
    #pragma unroll
    for (int g = 0; g < 8; ++g) s += partial[((size_t)n * 8 + g) * HWP + t];
    fre[t] = s;
  }
  __syncthreads();
  if (t < HWP) {
    float v = fre[t];
    int rank = 0;
    #pragma unroll 4
    for (int q = 0; q < HWP; ++q) {
      float u = fre[q];
      rank += ((u > v) || (u == v && q < t)) ? 1 : 0;
    }
    if (rank < 16) sc[rank] = t;                           // maxK: ranks 0..15
    else if (rank >= 89 && rank < 105) sc[rank - 73] = t;  // medK: ranks 89..104
  }
  __syncthreads();

  if (z == 0 && t < 32) {
    int p = sc[t];
    out[2 * NB * 4096 + n * 32 + t] = (float)(p / HH);            // rows
    out[2 * NB * 4096 + NB * 32 + n * 32 + t] = (float)(p % HH);  // cols
  }

  // ---- stage A (16 x 1024 bf16): coalesced 2KB row copies from xT ----
  {
    const int j = t >> 5;              // 16 rows
    const int g = t & 31;              // 32 chunks of 32 bf16 (64 B)
    const int sj = sc[z * 16 + j];
    const ushort_t* src = xT + ((size_t)n * HWP + sj) * CC + g * 32;
    ushort_t* dst = &A_sh[j * AP + g * 32];
    #pragma unroll
    for (int u = 0; u < 4; ++u)
      *reinterpret_cast<short8*>(dst + u * 8) =
          *reinterpret_cast<const short8*>(src + u * 8);
  }
  // ---- L matrix ----
  if (t < 256) {
    const int i = t >> 4, j = t & 15;
    int pi = sc[z * 16 + i], pj = sc[z * 16 + j];
    float dr = (float)(pi / HH - pj / HH);
    float dc = (float)(pi % HH - pj % HH);
    Lsh[i][j] = 1.0f / (1.0f + sqrtf(dr * dr + dc * dc));
  }
  __syncthreads();
  if (t < 16) {
    float s = 0.f;
    #pragma unroll
    for (int j = 0; j < 16; ++j) s += Lsh[t][j];
    dinv[t] = rsqrtf(s);
  }

  const int w = t >> 6;                  // 8 waves, 32 output cols each
  const int l = t & 63;
  const int m = l & 15;
  const int quad = l >> 4;

  const ushort_t* Arow = &A_sh[m * AP + quad * 8];
  const ushort_t* B0 = wb + (size_t)z * (OO * CC) + (size_t)(w * 32 + m) * CC + quad * 8;

  float4v acc0 = {0.f, 0.f, 0.f, 0.f};
  float4v acc1 = acc0;

  __syncthreads();   // dinv + A_sh visible

  #pragma unroll 4
  for (int k0 = 0; k0 < CC; k0 += 32) {
    short8 a  = *reinterpret_cast<const short8*>(Arow + k0);
    short8 b0 = *reinterpret_cast<const short8*>(B0 + k0);
    short8 b1 = *reinterpret_cast<const short8*>(B0 + 16 * CC + k0);
    acc0 = __builtin_amdgcn_mfma_f32_16x16x32_bf16(a, b0, acc0, 0, 0, 0);
    acc1 = __builtin_amdgcn_mfma_f32_16x16x32_bf16(a, b1, acc1, 0, 0, 0);
  }

  const float* gp = z ? g_med : g_max;
  const float* bp = z ? b_med : b_max;
  const float* mp = z ? m_med : m_max;
  const float* vp = z ? v_med : v_max;

  // BN + ReLU; scatter C-layout (col=lane&15, row=quad*4+reg) to LDS
  #pragma unroll
  for (int tt = 0; tt < 2; ++tt) {
    float4v av = tt ? acc1 : acc0;
    int o = w * 32 + tt * 16 + m;
    float scale = gp[o] * rsqrtf(vp[o] + 1e-5f);
    float shift = bp[o] - mp[o] * scale;
    #pragma unroll
    for (int r = 0; r < 4; ++r) {
      int j = quad * 4 + r;
      float y = av[r] * scale + shift;
      y = fmaxf(y, 0.f);
      y_sh[j][o] = y * dinv[j];
    }
  }
  __syncthreads();

  // out[n,z,i,o] = dinv_i * sum_j L[i][j] * (dinv_j * y[j][o])
  {
    const int o = t & 255;
    const int ih = (t >> 8) * 8;
    float yp[16];
    #pragma unroll
    for (int j = 0; j < 16; ++j) yp[j] = y_sh[j][o];
    float* ob = out + (size_t)z * (NB * 4096) + (size_t)n * 4096 + o;
    #pragma unroll
    for (int i2 = 0; i2 < 8; ++i2) {
      const int i = ih + i2;
      float s = 0.f;
      #pragma unroll
      for (int j = 0; j < 16; ++j) s = fmaf(Lsh[i][j], yp[j], s);
      ob[(size_t)i * OO] = s * dinv[i];
    }
  }
}

extern "C" void kernel_launch(void* const* d_in, const int* in_sizes, int n_in,
                              void* d_out, int out_size, void* d_ws, size_t ws_size,
                              hipStream_t stream) {
  const float* x     = (const float*)d_in[0];
  const float* w_max = (const float*)d_in[2];
  const float* g_max = (const float*)d_in[3];
  const float* b_max = (const float*)d_in[4];
  const float* m_max = (const float*)d_in[5];
  const float* v_max = (const float*)d_in[6];
  const float* w_med = (const float*)d_in[7];
  const float* g_med = (const float*)d_in[8];
  const float* b_med = (const float*)d_in[9];
  const float* m_med = (const float*)d_in[10];
  const float* v_med = (const float*)d_in[11];
  float* out = (float*)d_out;

  float* ws_f = (float*)d_ws;
  float* partial  = ws_f;                        // 128*8*196 = 200704 floats
  ushort_t* wb    = (ushort_t*)(ws_f + 200704);  // 2*256*1024 ushorts (1 MB)
  ushort_t* xT    = (ushort_t*)(ws_f + 462848);  // 128*196*1024 ushorts (51 MB)

  k_prep<<<dim3(256 + 2048 + 1024), 256, 0, stream>>>(x, w_max, w_med,
                                                      partial, wb, xT);
  k_main<<<dim3(NB, 2), 512, 0, stream>>>(xT, partial, wb,
                                          g_max, b_max, m_max, v_max,
                                          g_med, b_med, m_med, v_med, out);
}